// Round 1
// baseline (357.015 us; speedup 1.0000x reference)
//
#include <hip/hip_runtime.h>
#include <hip/hip_fp16.h>

#define N_AGENTS 8192
#define FDIM 128
#define PDIM 16
#define NEDGES 262144

typedef float floatx4 __attribute__((ext_vector_type(4)));

// ------------------------------------------------- per-row precompute (1 wave/row)
// T[row][0:128)  = fp16 row-L2-normalized next_feature
// T[row][128:256)= fp16 (feature - next_feature)
// scale[row] = (persona.alpha, persona.gamma/F)   brow[row] = persona.beta
__global__ __launch_bounds__(256) void row_prep_k(
        const float* __restrict__ feature,
        const float* __restrict__ next_feature,
        const float* __restrict__ persona,
        const float* __restrict__ alpha,
        const float* __restrict__ beta,
        const float* __restrict__ gamma,
        __half2* __restrict__ T2,
        float2* __restrict__ scale,
        float* __restrict__ brow) {
    int row  = (blockIdx.x * blockDim.x + threadIdx.x) >> 6;   // one wave64 per row
    int lane = threadIdx.x & 63;
    if (row >= N_AGENTS) return;

    const float2* f2 = (const float2*)(feature      + (size_t)row * FDIM);
    const float2* n2 = (const float2*)(next_feature + (size_t)row * FDIM);
    float2 f  = f2[lane];
    float2 nx = n2[lane];

    float2 d = make_float2(f.x - nx.x, f.y - nx.y);
    float ss = nx.x * nx.x + nx.y * nx.y;

    float pa = 0.f, pb = 0.f, pg = 0.f;
    if (lane < PDIM) {
        float p = persona[(size_t)row * PDIM + lane];
        pa = p * alpha[lane];
        pb = p * beta[lane];
        pg = p * gamma[lane];
    }

    #pragma unroll
    for (int off = 32; off > 0; off >>= 1) {
        ss += __shfl_xor(ss, off);
        pa += __shfl_xor(pa, off);
        pb += __shfl_xor(pb, off);
        pg += __shfl_xor(pg, off);
    }

    float inv = 1.0f / sqrtf(ss);
    __half2* trow = T2 + (size_t)row * 128;
    trow[lane]      = __float22half2_rn(make_float2(nx.x * inv, nx.y * inv)); // nf
    trow[64 + lane] = __float22half2_rn(d);                                   // diff

    if (lane == 0) {
        scale[row] = make_float2(pa, pg * (1.0f / FDIM));
        brow[row]  = pb;
    }
}

// 8 halves (one float4 chunk) fp16 dot, fp32 accumulate
__device__ inline float dot8(float4 a, float4 b) {
    const __half2* ha = (const __half2*)&a;
    const __half2* hb = (const __half2*)&b;
    float s = 0.f;
    #pragma unroll
    for (int j = 0; j < 4; ++j) {
        float2 fa = __half22float2(ha[j]);
        float2 fb = __half22float2(hb[j]);
        s += fa.x * fb.x + fa.y * fb.y;
    }
    return s;
}

// ------------------------------------------------- act edge values (streaming, no atomics)
// 16 lanes per edge; lanes 0-7 compute the nf·nf (sim) half, lanes 8-15 the
// diff·diff (imp) half. T (4 MiB) stays L2-resident: nothing else competes.
#define ACT_BLOCKS ((NEDGES * 16) / 256)
__global__ __launch_bounds__(256) void act_val_k(
        const int* __restrict__ asrc,
        const int* __restrict__ adst,
        const __half* __restrict__ T,
        const float2* __restrict__ scale,
        float* __restrict__ actval) {
    int gid    = blockIdx.x * 256 + threadIdx.x;
    int e      = gid >> 4;
    int lane16 = gid & 15;
    int s = asrc[e];
    int d = adst[e];
    const float4* ts = (const float4*)(T + (size_t)s * 256);
    const float4* td = (const float4*)(T + (size_t)d * 256);
    int i0 = lane16 * 2;          // lanes 0-7: nf chunks 0..15 ; lanes 8-15: diff 16..31
    float acc = dot8(ts[i0], td[i0]) + dot8(ts[i0 + 1], td[i0 + 1]);
    acc += __shfl_xor(acc, 1, 16);
    acc += __shfl_xor(acc, 2, 16);
    acc += __shfl_xor(acc, 4, 16);        // lanes 0-7 = sim, 8-15 = imp
    float other = __shfl_xor(acc, 8, 16); // on lane 0: imp
    if (lane16 == 0) {
        float2 sc = scale[s];
        actval[e] = acc * sc.x + other * sc.y;
    }
}

// ------------------------------------------------- scatter into zeroed output
// 524K direct fp32 atomics. Touched lines ~512K x 128B RMW ~= 67 MB of HBM
// traffic; latency hidden by 8192 waves. Kept separate from act_val_k so the
// atomic line churn doesn't evict T from L2 during the gather phase.
__global__ __launch_bounds__(256) void scatter_k(
        const int* __restrict__ asrc,
        const int* __restrict__ adst,
        const float* __restrict__ actval,
        const int* __restrict__ esrc,
        const int* __restrict__ edst,
        const float* __restrict__ brow,
        float* __restrict__ out) {
    int t = blockIdx.x * 256 + threadIdx.x;
    if (t < NEDGES) {
        atomicAdd(out + (size_t)asrc[t] * N_AGENTS + adst[t], actval[t]);
    } else {
        int e = t - NEDGES;
        int s = esrc[e];
        atomicAdd(out + (size_t)s * N_AGENTS + edst[e], -brow[s]);
    }
}

// ---------------------------------------------------------------- launcher
extern "C" void kernel_launch(void* const* d_in, const int* in_sizes, int n_in,
                              void* d_out, int out_size, void* d_ws, size_t ws_size,
                              hipStream_t stream) {
    const float* feature      = (const float*)d_in[0];
    const float* next_feature = (const float*)d_in[1];
    const float* persona      = (const float*)d_in[2];
    const float* alpha        = (const float*)d_in[3];
    const float* beta         = (const float*)d_in[4];
    const float* gamma        = (const float*)d_in[5];
    const int*   act_src      = (const int*)d_in[6];
    const int*   act_dst      = (const int*)d_in[7];
    const int*   edge_src     = (const int*)d_in[8];
    const int*   edge_dst     = (const int*)d_in[9];

    float* out = (float*)d_out;

    // ws layout:
    //   T      : N*256 half  = 4 MiB   (L2-resident gather table)
    //   scale  : N float2    = 64 KiB
    //   brow   : N float     = 32 KiB
    //   actval : E float     = 1 MiB
    char* ws = (char*)d_ws;
    __half* T      = (__half*)ws;   ws += (size_t)N_AGENTS * 256 * sizeof(__half);
    float2* scale  = (float2*)ws;   ws += (size_t)N_AGENTS * sizeof(float2);
    float*  brow   = (float*)ws;    ws += (size_t)N_AGENTS * sizeof(float);
    float*  actval = (float*)ws;

    // 1) per-row precompute
    row_prep_k<<<N_AGENTS / 4, 256, 0, stream>>>(
        feature, next_feature, persona, alpha, beta, gamma,
        (__half2*)T, scale, brow);

    // 2) act-edge dot products -> compact value stream (T stays hot in L2)
    act_val_k<<<ACT_BLOCKS, 256, 0, stream>>>(
        act_src, act_dst, T, scale, actval);

    // 3) zero the dense output via the runtime fill kernel (measured 6.3 TB/s)
    hipMemsetAsync(out, 0, (size_t)N_AGENTS * N_AGENTS * sizeof(float), stream);

    // 4) direct atomic scatter of both edge lists into the output
    scatter_k<<<(2 * NEDGES) / 256, 256, 0, stream>>>(
        act_src, act_dst, actval, edge_src, edge_dst, brow, out);
}

// Round 2
// 331.583 us; speedup vs baseline: 1.0767x; 1.0767x over previous
//
#include <hip/hip_runtime.h>
#include <hip/hip_fp16.h>

#define N_AGENTS 8192
#define FDIM 128
#define PDIM 16
#define NEDGES 262144
#define CAP 128          // per-row per-list capacity; degree ~ Poisson(32), max ~65 << 128
#define OVERCAP 4096     // safety overflow list (normally empty)

typedef float floatx4 __attribute__((ext_vector_type(4)));

// ------------------------------------------------- per-row precompute (1 wave/row)
// T[row][0:128)  = fp16 row-L2-normalized next_feature
// T[row][128:256)= fp16 (feature - next_feature)
// scale[row] = (persona.alpha, persona.gamma/F)   brow[row] = persona.beta
// Also zeroes the per-row bin counters and (thread 0) the overflow counter.
__global__ __launch_bounds__(256) void row_prep_k(
        const float* __restrict__ feature,
        const float* __restrict__ next_feature,
        const float* __restrict__ persona,
        const float* __restrict__ alpha,
        const float* __restrict__ beta,
        const float* __restrict__ gamma,
        __half2* __restrict__ T2,
        float2* __restrict__ scale,
        float* __restrict__ brow,
        int* __restrict__ cntA,
        int* __restrict__ cntC,
        int* __restrict__ ocnt) {
    int row  = (blockIdx.x * blockDim.x + threadIdx.x) >> 6;   // one wave64 per row
    int lane = threadIdx.x & 63;
    if (blockIdx.x == 0 && threadIdx.x == 0) *ocnt = 0;
    if (row >= N_AGENTS) return;

    const float2* f2 = (const float2*)(feature      + (size_t)row * FDIM);
    const float2* n2 = (const float2*)(next_feature + (size_t)row * FDIM);
    float2 f  = f2[lane];
    float2 nx = n2[lane];

    float2 d = make_float2(f.x - nx.x, f.y - nx.y);
    float ss = nx.x * nx.x + nx.y * nx.y;

    float pa = 0.f, pb = 0.f, pg = 0.f;
    if (lane < PDIM) {
        float p = persona[(size_t)row * PDIM + lane];
        pa = p * alpha[lane];
        pb = p * beta[lane];
        pg = p * gamma[lane];
    }

    #pragma unroll
    for (int off = 32; off > 0; off >>= 1) {
        ss += __shfl_xor(ss, off);
        pa += __shfl_xor(pa, off);
        pb += __shfl_xor(pb, off);
        pg += __shfl_xor(pg, off);
    }

    float inv = 1.0f / sqrtf(ss);
    __half2* trow = T2 + (size_t)row * 128;
    trow[lane]      = __float22half2_rn(make_float2(nx.x * inv, nx.y * inv)); // nf
    trow[64 + lane] = __float22half2_rn(d);                                   // diff

    if (lane == 0) {
        scale[row] = make_float2(pa, pg * (1.0f / FDIM));
        brow[row]  = pb;
        cntA[row]  = 0;
        cntC[row]  = 0;
    }
}

// 8 halves (one float4 chunk) fp16 dot, fp32 accumulate
__device__ inline float dot8(float4 a, float4 b) {
    const __half2* ha = (const __half2*)&a;
    const __half2* hb = (const __half2*)&b;
    float s = 0.f;
    #pragma unroll
    for (int j = 0; j < 4; ++j) {
        float2 fa = __half22float2(ha[j]);
        float2 fb = __half22float2(hb[j]);
        s += fa.x * fb.x + fa.y * fb.y;
    }
    return s;
}

// ------------------------------------------------- bin destination indices by source row
// Records are 4 B (just the dst index) — values are computed later, inline in
// row_assemble_k. binsA/binsC (8 MiB total) are written once and read once in
// the immediately-following kernel: they live in L2.
__global__ __launch_bounds__(256) void edge_bin_k(
        const int* __restrict__ asrc,
        const int* __restrict__ adst,
        const int* __restrict__ esrc,
        const int* __restrict__ edst,
        int* __restrict__ cntA,
        int* __restrict__ cntC,
        int* __restrict__ binsA,
        int* __restrict__ binsC,
        int* __restrict__ ocnt,
        int4* __restrict__ olist) {
    int t = blockIdx.x * 256 + threadIdx.x;
    if (t < NEDGES) {                       // act edges
        int s = asrc[t];
        int d = adst[t];
        int pos = atomicAdd(&cntA[s], 1);
        if (pos < CAP) binsA[(size_t)s * CAP + pos] = d;
        else { int op = atomicAdd(ocnt, 1); if (op < OVERCAP) olist[op] = make_int4(s, d, 0, 0); }
    } else {                                // cost edges
        int e = t - NEDGES;
        int s = esrc[e];
        int d = edst[e];
        int pos = atomicAdd(&cntC[s], 1);
        if (pos < CAP) binsC[(size_t)s * CAP + pos] = d;
        else { int op = atomicAdd(ocnt, 1); if (op < OVERCAP) olist[op] = make_int4(s, d, 1, 0); }
    }
}

// ------------------------------------------------- assemble: one block per row
// Computes act-edge dot products INLINE (T[r] fragment in registers, T[d]
// gathered from L2 — 16 lanes per edge), applies cost edges, then writes the
// row once, nontemporally. No memset of the output, no value round-trip.
__global__ __launch_bounds__(256) void row_assemble_k(
        const int* __restrict__ cntA,
        const int* __restrict__ binsA,
        const int* __restrict__ cntC,
        const int* __restrict__ binsC,
        const __half* __restrict__ T,
        const float2* __restrict__ scale,
        const float* __restrict__ brow,
        float* __restrict__ out) {
    __shared__ float rowbuf[N_AGENTS];
    int r   = blockIdx.x;
    int tid = threadIdx.x;

    floatx4* rb4 = (floatx4*)rowbuf;
    floatx4 z = (floatx4)0.f;
    #pragma unroll
    for (int i = 0; i < 8; ++i)                   // 2048 float4 / 256 threads
        rb4[tid + i * 256] = z;

    int grp    = tid >> 4;                        // 16 edge-groups per block
    int lane16 = tid & 15;
    int i0     = lane16 * 2;  // lanes 0-7: nf chunks 0..15 ; lanes 8-15: diff 16..31
    const float4* tr = (const float4*)(T + (size_t)r * 256);
    float4 tsA = tr[i0];                          // this row's T fragment, in regs
    float4 tsB = tr[i0 + 1];
    float2 sc  = scale[r];
    float  br  = brow[r];
    int cA = cntA[r]; cA = cA < CAP ? cA : CAP;
    int cC = cntC[r]; cC = cC < CAP ? cC : CAP;
    __syncthreads();                              // rowbuf zeroed

    for (int i = grp; i < cA; i += 16) {
        int d = binsA[(size_t)r * CAP + i];
        const float4* td = (const float4*)(T + (size_t)d * 256);
        float acc = dot8(tsA, td[i0]) + dot8(tsB, td[i0 + 1]);
        acc += __shfl_xor(acc, 1, 16);
        acc += __shfl_xor(acc, 2, 16);
        acc += __shfl_xor(acc, 4, 16);            // lanes 0-7 = sim, 8-15 = imp
        float other = __shfl_xor(acc, 8, 16);     // on lane 0: imp
        if (lane16 == 0)
            atomicAdd(&rowbuf[d], acc * sc.x + other * sc.y);
    }
    for (int i = tid; i < cC; i += 256)
        atomicAdd(&rowbuf[binsC[(size_t)r * CAP + i]], -br);
    __syncthreads();

    // output is written once and never re-read: stream past L2
    floatx4* dst = (floatx4*)(out + (size_t)r * N_AGENTS);
    #pragma unroll
    for (int i = 0; i < 8; ++i)
        __builtin_nontemporal_store(rb4[tid + i * 256], &dst[tid + i * 256]);
}

// ------------------------------------------------- overflow fixup (normally empty)
__global__ __launch_bounds__(256) void overflow_k(
        const int* __restrict__ ocnt,
        const int4* __restrict__ olist,
        const __half* __restrict__ T,
        const float2* __restrict__ scale,
        const float* __restrict__ brow,
        float* __restrict__ out) {
    int n = *ocnt;
    n = n < OVERCAP ? n : OVERCAP;
    int grp    = threadIdx.x >> 4;
    int lane16 = threadIdx.x & 15;
    int i0     = lane16 * 2;
    for (int i = grp; i < n; i += 16) {
        int4 rec = olist[i];
        if (rec.z) {                               // cost edge
            if (lane16 == 0)
                atomicAdd(out + (size_t)rec.x * N_AGENTS + rec.y, -brow[rec.x]);
        } else {                                   // act edge: recompute dot
            const float4* ts = (const float4*)(T + (size_t)rec.x * 256);
            const float4* td = (const float4*)(T + (size_t)rec.y * 256);
            float acc = dot8(ts[i0], td[i0]) + dot8(ts[i0 + 1], td[i0 + 1]);
            acc += __shfl_xor(acc, 1, 16);
            acc += __shfl_xor(acc, 2, 16);
            acc += __shfl_xor(acc, 4, 16);
            float other = __shfl_xor(acc, 8, 16);
            if (lane16 == 0) {
                float2 sc = scale[rec.x];
                atomicAdd(out + (size_t)rec.x * N_AGENTS + rec.y,
                          acc * sc.x + other * sc.y);
            }
        }
    }
}

// ---------------------------------------------------------------- launcher
extern "C" void kernel_launch(void* const* d_in, const int* in_sizes, int n_in,
                              void* d_out, int out_size, void* d_ws, size_t ws_size,
                              hipStream_t stream) {
    const float* feature      = (const float*)d_in[0];
    const float* next_feature = (const float*)d_in[1];
    const float* persona      = (const float*)d_in[2];
    const float* alpha        = (const float*)d_in[3];
    const float* beta         = (const float*)d_in[4];
    const float* gamma        = (const float*)d_in[5];
    const int*   act_src      = (const int*)d_in[6];
    const int*   act_dst      = (const int*)d_in[7];
    const int*   edge_src     = (const int*)d_in[8];
    const int*   edge_dst     = (const int*)d_in[9];

    float* out = (float*)d_out;

    // ws layout:
    //   T     : N*256 half   = 4 MiB   (L2-resident gather table)
    //   scale : N float2     = 64 KiB
    //   brow  : N float      = 32 KiB
    //   cntA  : N int        = 32 KiB
    //   cntC  : N int        = 32 KiB
    //   binsA : N*CAP int    = 4 MiB   (act-edge dst indices, L2)
    //   binsC : N*CAP int    = 4 MiB   (cost-edge dst indices, L2)
    //   ocnt  : 1 int (pad 16B)
    //   olist : OVERCAP int4 = 64 KiB
    char* ws = (char*)d_ws;
    __half* T     = (__half*)ws;   ws += (size_t)N_AGENTS * 256 * sizeof(__half);
    float2* scale = (float2*)ws;   ws += (size_t)N_AGENTS * sizeof(float2);
    float*  brow  = (float*)ws;    ws += (size_t)N_AGENTS * sizeof(float);
    int*    cntA  = (int*)ws;      ws += (size_t)N_AGENTS * sizeof(int);
    int*    cntC  = (int*)ws;      ws += (size_t)N_AGENTS * sizeof(int);
    int*    binsA = (int*)ws;      ws += (size_t)N_AGENTS * CAP * sizeof(int);
    int*    binsC = (int*)ws;      ws += (size_t)N_AGENTS * CAP * sizeof(int);
    int*    ocnt  = (int*)ws;      ws += 16;
    int4*   olist = (int4*)ws;

    // 1) per-row precompute + counter zeroing
    row_prep_k<<<N_AGENTS / 4, 256, 0, stream>>>(
        feature, next_feature, persona, alpha, beta, gamma,
        (__half2*)T, scale, brow, cntA, cntC, ocnt);

    // 2) bin destination indices by source row (both edge lists, 4 B records)
    edge_bin_k<<<(2 * NEDGES) / 256, 256, 0, stream>>>(
        act_src, act_dst, edge_src, edge_dst,
        cntA, cntC, binsA, binsC, ocnt, olist);

    // 3) per-row: inline dots + cost edges in LDS, single coalesced NT write
    row_assemble_k<<<N_AGENTS, 256, 0, stream>>>(
        cntA, binsA, cntC, binsC, T, scale, brow, out);

    // 4) overflow fixup (no-op for this input; kept for robustness)
    overflow_k<<<1, 256, 0, stream>>>(ocnt, olist, T, scale, brow, out);
}

// Round 3
// 328.854 us; speedup vs baseline: 1.0856x; 1.0083x over previous
//
#include <hip/hip_runtime.h>
#include <hip/hip_fp16.h>

#define N_AGENTS 8192
#define FDIM 128
#define PDIM 16
#define NEDGES 262144
#define CAP 128          // per-row per-list capacity; degree ~ Poisson(32), max ~65 << 128
#define OVERCAP 4096     // safety overflow list (normally empty)

typedef float floatx4 __attribute__((ext_vector_type(4)));

// 8 halves (one float4 chunk) fp16 dot, fp32 accumulate
__device__ inline float dot8(float4 a, float4 b) {
    const __half2* ha = (const __half2*)&a;
    const __half2* hb = (const __half2*)&b;
    float s = 0.f;
    #pragma unroll
    for (int j = 0; j < 4; ++j) {
        float2 fa = __half22float2(ha[j]);
        float2 fb = __half22float2(hb[j]);
        s += fa.x * fb.x + fa.y * fb.y;
    }
    return s;
}

// ------------------------------------------------- merged prep + bin
// Even blocks: per-row precompute (one wave64 per row).
//   T[row][0:128)  = fp16 row-L2-normalized next_feature
//   T[row][128:256)= fp16 (feature - next_feature)
//   scale[row] = (persona.alpha, persona.gamma/F)   brow[row] = persona.beta
// Odd blocks: bin destination indices by source row (4 B records, stay in L2).
// The two roles are data-independent (counters are pre-zeroed by a memset),
// so they run CONCURRENTLY — prep's streaming reads overlap bin's atomics.
#define PREP_BLOCKS (N_AGENTS / 4)          // 2048
#define BIN_BLOCKS  ((2 * NEDGES) / 256)    // 2048
__global__ __launch_bounds__(256) void prep_bin_k(
        const float* __restrict__ feature,
        const float* __restrict__ next_feature,
        const float* __restrict__ persona,
        const float* __restrict__ alpha,
        const float* __restrict__ beta,
        const float* __restrict__ gamma,
        __half2* __restrict__ T2,
        float2* __restrict__ scale,
        float* __restrict__ brow,
        const int* __restrict__ asrc,
        const int* __restrict__ adst,
        const int* __restrict__ esrc,
        const int* __restrict__ edst,
        int* __restrict__ cntA,
        int* __restrict__ cntC,
        int* __restrict__ binsA,
        int* __restrict__ binsC,
        int* __restrict__ ocnt,
        int4* __restrict__ olist) {
    int bid = blockIdx.x >> 1;
    if ((blockIdx.x & 1) == 0) {
        // ---- role 0: row prep, 4 rows per block ----
        int row  = bid * 4 + (threadIdx.x >> 6);
        int lane = threadIdx.x & 63;

        const float2* f2 = (const float2*)(feature      + (size_t)row * FDIM);
        const float2* n2 = (const float2*)(next_feature + (size_t)row * FDIM);
        float2 f  = f2[lane];
        float2 nx = n2[lane];

        float2 d = make_float2(f.x - nx.x, f.y - nx.y);
        float ss = nx.x * nx.x + nx.y * nx.y;

        float pa = 0.f, pb = 0.f, pg = 0.f;
        if (lane < PDIM) {
            float p = persona[(size_t)row * PDIM + lane];
            pa = p * alpha[lane];
            pb = p * beta[lane];
            pg = p * gamma[lane];
        }

        #pragma unroll
        for (int off = 32; off > 0; off >>= 1) {
            ss += __shfl_xor(ss, off);
            pa += __shfl_xor(pa, off);
            pb += __shfl_xor(pb, off);
            pg += __shfl_xor(pg, off);
        }

        float inv = 1.0f / sqrtf(ss);
        __half2* trow = T2 + (size_t)row * 128;
        trow[lane]      = __float22half2_rn(make_float2(nx.x * inv, nx.y * inv)); // nf
        trow[64 + lane] = __float22half2_rn(d);                                   // diff

        if (lane == 0) {
            scale[row] = make_float2(pa, pg * (1.0f / FDIM));
            brow[row]  = pb;
        }
    } else {
        // ---- role 1: edge binning (counters pre-zeroed by memset) ----
        int t = bid * 256 + threadIdx.x;
        if (t < NEDGES) {                       // act edges
            int s = asrc[t];
            int d = adst[t];
            int pos = atomicAdd(&cntA[s], 1);
            if (pos < CAP) binsA[(size_t)s * CAP + pos] = d;
            else { int op = atomicAdd(ocnt, 1); if (op < OVERCAP) olist[op] = make_int4(s, d, 0, 0); }
        } else {                                // cost edges
            int e = t - NEDGES;
            int s = esrc[e];
            int d = edst[e];
            int pos = atomicAdd(&cntC[s], 1);
            if (pos < CAP) binsC[(size_t)s * CAP + pos] = d;
            else { int op = atomicAdd(ocnt, 1); if (op < OVERCAP) olist[op] = make_int4(s, d, 1, 0); }
        }
    }
}

// ------------------------------------------------- assemble: one block per row
// Computes act-edge dot products INLINE (T[r] fragment in registers, T[d]
// gathered from L2 — 16 lanes per edge), applies cost edges, handles the
// (normally empty) overflow list, then writes the row once, nontemporally.
__global__ __launch_bounds__(256) void row_assemble_k(
        const int* __restrict__ cntA,
        const int* __restrict__ binsA,
        const int* __restrict__ cntC,
        const int* __restrict__ binsC,
        const __half* __restrict__ T,
        const float2* __restrict__ scale,
        const float* __restrict__ brow,
        const int* __restrict__ ocnt,
        const int4* __restrict__ olist,
        float* __restrict__ out) {
    __shared__ float rowbuf[N_AGENTS];
    int r   = blockIdx.x;
    int tid = threadIdx.x;

    floatx4* rb4 = (floatx4*)rowbuf;
    floatx4 z = (floatx4)0.f;
    #pragma unroll
    for (int i = 0; i < 8; ++i)                   // 2048 float4 / 256 threads
        rb4[tid + i * 256] = z;

    int grp    = tid >> 4;                        // 16 edge-groups per block
    int lane16 = tid & 15;
    int i0     = lane16 * 2;  // lanes 0-7: nf chunks 0..15 ; lanes 8-15: diff 16..31
    const float4* tr = (const float4*)(T + (size_t)r * 256);
    float4 tsA = tr[i0];                          // this row's T fragment, in regs
    float4 tsB = tr[i0 + 1];
    float2 sc  = scale[r];
    float  br  = brow[r];
    int cA = cntA[r]; cA = cA < CAP ? cA : CAP;
    int cC = cntC[r]; cC = cC < CAP ? cC : CAP;
    int nov = *ocnt;                              // one L2-broadcast read per block
    nov = nov < OVERCAP ? nov : OVERCAP;
    __syncthreads();                              // rowbuf zeroed

    for (int i = grp; i < cA; i += 16) {
        int d = binsA[(size_t)r * CAP + i];
        const float4* td = (const float4*)(T + (size_t)d * 256);
        float acc = dot8(tsA, td[i0]) + dot8(tsB, td[i0 + 1]);
        acc += __shfl_xor(acc, 1, 16);
        acc += __shfl_xor(acc, 2, 16);
        acc += __shfl_xor(acc, 4, 16);            // lanes 0-7 = sim, 8-15 = imp
        float other = __shfl_xor(acc, 8, 16);     // on lane 0: imp
        if (lane16 == 0)
            atomicAdd(&rowbuf[d], acc * sc.x + other * sc.y);
    }
    for (int i = tid; i < cC; i += 256)
        atomicAdd(&rowbuf[binsC[(size_t)r * CAP + i]], -br);

    if (nov > 0) {                                // fused overflow fixup (normally skipped)
        for (int i = grp; i < nov; i += 16) {
            int4 rec = olist[i];
            if (rec.x != r) continue;
            if (rec.z) {                          // cost edge
                if (lane16 == 0) atomicAdd(&rowbuf[rec.y], -br);
            } else {                              // act edge: recompute dot
                const float4* td = (const float4*)(T + (size_t)rec.y * 256);
                float acc = dot8(tsA, td[i0]) + dot8(tsB, td[i0 + 1]);
                acc += __shfl_xor(acc, 1, 16);
                acc += __shfl_xor(acc, 2, 16);
                acc += __shfl_xor(acc, 4, 16);
                float other = __shfl_xor(acc, 8, 16);
                if (lane16 == 0)
                    atomicAdd(&rowbuf[rec.y], acc * sc.x + other * sc.y);
            }
        }
    }
    __syncthreads();

    // output is written once and never re-read: stream past L2
    floatx4* dst = (floatx4*)(out + (size_t)r * N_AGENTS);
    #pragma unroll
    for (int i = 0; i < 8; ++i)
        __builtin_nontemporal_store(rb4[tid + i * 256], &dst[tid + i * 256]);
}

// ---------------------------------------------------------------- launcher
extern "C" void kernel_launch(void* const* d_in, const int* in_sizes, int n_in,
                              void* d_out, int out_size, void* d_ws, size_t ws_size,
                              hipStream_t stream) {
    const float* feature      = (const float*)d_in[0];
    const float* next_feature = (const float*)d_in[1];
    const float* persona      = (const float*)d_in[2];
    const float* alpha        = (const float*)d_in[3];
    const float* beta         = (const float*)d_in[4];
    const float* gamma        = (const float*)d_in[5];
    const int*   act_src      = (const int*)d_in[6];
    const int*   act_dst      = (const int*)d_in[7];
    const int*   edge_src     = (const int*)d_in[8];
    const int*   edge_dst     = (const int*)d_in[9];

    float* out = (float*)d_out;

    // ws layout:
    //   T     : N*256 half   = 4 MiB   (L2-resident gather table)
    //   scale : N float2     = 64 KiB
    //   brow  : N float      = 32 KiB
    //   cntA  : N int        = 32 KiB  \
    //   cntC  : N int        = 32 KiB   } one contiguous memset region
    //   ocnt  : 1 int (pad 16B)        /
    //   binsA : N*CAP int    = 4 MiB   (act-edge dst indices, L2)
    //   binsC : N*CAP int    = 4 MiB   (cost-edge dst indices, L2)
    //   olist : OVERCAP int4 = 64 KiB
    char* ws = (char*)d_ws;
    __half* T     = (__half*)ws;   ws += (size_t)N_AGENTS * 256 * sizeof(__half);
    float2* scale = (float2*)ws;   ws += (size_t)N_AGENTS * sizeof(float2);
    float*  brow  = (float*)ws;    ws += (size_t)N_AGENTS * sizeof(float);
    int*    cntA  = (int*)ws;      ws += (size_t)N_AGENTS * sizeof(int);
    int*    cntC  = (int*)ws;      ws += (size_t)N_AGENTS * sizeof(int);
    int*    ocnt  = (int*)ws;      ws += 16;
    int*    binsA = (int*)ws;      ws += (size_t)N_AGENTS * CAP * sizeof(int);
    int*    binsC = (int*)ws;      ws += (size_t)N_AGENTS * CAP * sizeof(int);
    int4*   olist = (int4*)ws;

    // 1) zero counters (tiny: 64 KiB + 16 B) — removes the prep->bin ordering
    hipMemsetAsync(cntA, 0, 2 * (size_t)N_AGENTS * sizeof(int) + 16, stream);

    // 2) prep rows (even blocks) CONCURRENT with edge binning (odd blocks)
    prep_bin_k<<<PREP_BLOCKS + BIN_BLOCKS, 256, 0, stream>>>(
        feature, next_feature, persona, alpha, beta, gamma,
        (__half2*)T, scale, brow,
        act_src, act_dst, edge_src, edge_dst,
        cntA, cntC, binsA, binsC, ocnt, olist);

    // 3) per-row: inline dots + cost edges (+ fused overflow) in LDS,
    //    single coalesced NT write of the output row
    row_assemble_k<<<N_AGENTS, 256, 0, stream>>>(
        cntA, binsA, cntC, binsC, T, scale, brow, ocnt, olist, out);
}